// Round 16
// baseline (955.134 us; speedup 1.0000x reference)
//
#include <hip/hip_runtime.h>

typedef unsigned short ushort_t;
typedef __attribute__((ext_vector_type(8))) short short8;
typedef __attribute__((ext_vector_type(4))) float f32x4;

#define MTOT 28672   // B*S = 8*3584
#define H_   1024

static __device__ __forceinline__ float b2f(ushort_t u) {
    return __uint_as_float(((unsigned)u) << 16);
}
static __device__ __forceinline__ ushort_t f2b(float f) {
    unsigned u = __float_as_uint(f);
    u += 0x7fffu + ((u >> 16) & 1u);
    return (ushort_t)(u >> 16);
}

#define GLOAD(src, dst) __builtin_amdgcn_global_load_lds( \
    (const __attribute__((address_space(1))) void*)(src), \
    (__attribute__((address_space(3))) void*)(dst), 16, 0, 0)
#define MFMA16(a, b, c) __builtin_amdgcn_mfma_f32_16x16x32_bf16(a, b, c, 0, 0, 0)
#define LGKM0_FENCE() do { \
    asm volatile("s_waitcnt lgkmcnt(0)" ::: "memory"); \
    __builtin_amdgcn_sched_barrier(0); } while (0)

// ---------------- fp32 -> bf16 conversion (n % 1024 == 0), 4 elems/thread ----------------
__global__ __launch_bounds__(256)
void f2b_kernel(const float* __restrict__ in, ushort_t* __restrict__ out)
{
    size_t i = (size_t)blockIdx.x * 256 + threadIdx.x;
    float4 v = ((const float4*)in)[i];
    ushort4 o;
    o.x = f2b(v.x); o.y = f2b(v.y); o.z = f2b(v.z); o.w = f2b(v.w);
    ((ushort4*)out)[i] = o;
}

// ---------------- merged weight conversion: 4 segments, one launch ----------------
__global__ __launch_bounds__(256)
void f2b4_kernel(const float* __restrict__ s0, ushort_t* __restrict__ d0,
                 const float* __restrict__ s1, ushort_t* __restrict__ d1,
                 const float* __restrict__ s2, ushort_t* __restrict__ d2,
                 const float* __restrict__ s3, ushort_t* __restrict__ d3)
{
    size_t i = (size_t)blockIdx.x * 256 + threadIdx.x;   // grid = 12288 blocks exactly
    const float* s; ushort_t* d; size_t off;
    if (i < 786432)            { s = s0; d = d0; off = i; }
    else if (i < 1048576)      { s = s1; d = d1; off = i - 786432; }
    else if (i < 2097152)      { s = s2; d = d2; off = i - 1048576; }
    else                       { s = s3; d = d3; off = i - 2097152; }
    float4 v = ((const float4*)s)[off];
    ushort4 o;
    o.x = f2b(v.x); o.y = f2b(v.y); o.z = f2b(v.z); o.w = f2b(v.w);
    ((ushort4*)d)[off] = o;
}

// ---------------- bf16 GEMM v11 "80KB co-residency": BM=BN=256, BK=32, 8 waves --------
// v7's counted-vmcnt phase discipline at 80 KB LDS -> 2 blocks/CU possible (VGPR ~104).
// LDS: A dbuf (2x16K @ byte 0,16384) + B tri-buf (3x16K @ 32768,49152,65536).
// Per K32 step, 2 phases:
//  ph0: 12 ds_read (A[t&1],B[t%3], resident since ph1(t-1) vmcnt) ; stage A(t+1) ;
//       barrier ; lgkmcnt(0)+sched_barrier ; setprio'd 16 MFMA (avlo).
//  ph1: stage B(t+2) ; vmcnt(2) [waits A(t+1)+B(t+1) landed, leaves B(t+2) in flight --
//       never full-drain in steady state] ; barrier ; 16 MFMA (avhi).
// WAR audit: staged buffer last read >=1 barrier earlier; reads lgkm-fenced before the
// consuming MFMA which precedes that barrier. Tail: vmcnt(0) at t=NT-2, NT-1.
// Epilogue: two 128-row halves through first 64 KB (v10b pattern).
template<int EPI, typename ResT>
__global__ __launch_bounds__(512, 1)
void gemm_bt(const ushort_t* __restrict__ A, const ushort_t* __restrict__ Bt,
             const float* __restrict__ bias, const ResT* __restrict__ Res,
             ushort_t* __restrict__ C, int N, int K, int GX)
{
    __shared__ __align__(16) ushort_t lds[40960];   // 80 KB
    const int tid  = threadIdx.x;
    const int wave = tid >> 6;
    const int lane = tid & 63;
    const int wm = wave >> 2, wn = wave & 3;   // 2x4 waves, each 128 rows x 64 cols
    const int fr = lane & 15, kg = lane >> 4;

    // bijective XCD-chunked swizzle (m204 form)
    const int nwg = gridDim.x;
    const int xcd = blockIdx.x & 7, ofs = blockIdx.x >> 3;
    const int q8 = nwg >> 3, r8 = nwg & 7;
    const int wg = (xcd < r8 ? xcd * (q8 + 1) : r8 * (q8 + 1) + (xcd - r8) * q8) + ofs;
    const long row0 = (long)(wg / GX) * 256;
    const long col0 = (long)(wg % GX) * 256;

    const int NT = K >> 5;   // K32 steps (NT >= 32 here)

    // staging: per region 1024 chunks = 512 threads x 2 rounds (round1 = +128 rows)
    const int sr_ = tid >> 2;
    const int kk_ = (tid & 3) ^ ((sr_ >> 1) & 3);
    const ushort_t* pa = A  + (row0 + sr_) * (size_t)K + kk_ * 8;
    const ushort_t* pb = Bt + (col0 + sr_) * (size_t)K + kk_ * 8;
    const size_t rstep = (size_t)128 * K;

    char* const Lb = (char*)&lds[0];
    #define ABUF(i) (Lb + (i) * 16384)
    #define BBUF(i) (Lb + 32768 + (i) * 16384)
    #define STAGE_A(bufp, tt) do { \
        ushort_t* d_ = (ushort_t*)(bufp) + wave * 512; \
        GLOAD(pa + (size_t)(tt) * 32, d_); \
        GLOAD(pa + (size_t)(tt) * 32 + rstep, d_ + 4096); } while (0)
    #define STAGE_B(bufp, tt) do { \
        ushort_t* d_ = (ushort_t*)(bufp) + wave * 512; \
        GLOAD(pb + (size_t)(tt) * 32, d_); \
        GLOAD(pb + (size_t)(tt) * 32 + rstep, d_ + 4096); } while (0)

    // prologue: A(0), B(0), B(1) in strict issue order; wait A(0),B(0) (leave B(1))
    STAGE_A(ABUF(0), 0);
    STAGE_B(BBUF(0), 0);
    STAGE_B(BBUF(1), 1);
    asm volatile("s_waitcnt vmcnt(2)" ::: "memory");
    asm volatile("s_barrier" ::: "memory");

    // per-lane ds_read byte offsets within a 16 KB region
    const int pos2  = kg ^ ((fr >> 1) & 3);
    const int abase = (wm * 128 + fr) * 64 + pos2 * 16;   // + m*1024
    const int bbase = (wn * 64  + fr) * 64 + pos2 * 16;   // + n*1024

    f32x4 acc[8][4] = {};

    for (int t = 0; t < NT; ++t) {
        const char* rA = ABUF(t & 1);
        const char* rB = BBUF(t % 3);
        short8 bv[4], avlo[4], avhi[4];

        // ===== phase 0: all 12 reads; stage A(t+1); 16 MFMA (m0-3) =====
        #pragma unroll
        for (int j = 0; j < 4; ++j) bv[j]   = *(const short8*)(rB + bbase + j * 1024);
        #pragma unroll
        for (int i = 0; i < 4; ++i) avlo[i] = *(const short8*)(rA + abase + i * 1024);
        #pragma unroll
        for (int i = 0; i < 4; ++i) avhi[i] = *(const short8*)(rA + abase + (4 + i) * 1024);
        if (t + 1 < NT) STAGE_A(ABUF((t + 1) & 1), t + 1);
        asm volatile("s_barrier" ::: "memory");
        LGKM0_FENCE();
        __builtin_amdgcn_s_setprio(1);
        #pragma unroll
        for (int i = 0; i < 4; ++i)
            #pragma unroll
            for (int j = 0; j < 4; ++j) acc[i][j] = MFMA16(bv[j], avlo[i], acc[i][j]);
        __builtin_amdgcn_s_setprio(0);

        // ===== phase 1: stage B(t+2); counted vmcnt; 16 MFMA (m4-7) =====
        if (t + 2 < NT) {
            STAGE_B(BBUF((t + 2) % 3), t + 2);
            asm volatile("s_waitcnt vmcnt(2)" ::: "memory");   // A(t+1),B(t+1) landed
        } else {
            asm volatile("s_waitcnt vmcnt(0)" ::: "memory");   // tail drain
        }
        asm volatile("s_barrier" ::: "memory");
        __builtin_amdgcn_s_setprio(1);
        #pragma unroll
        for (int i = 0; i < 4; ++i)
            #pragma unroll
            for (int j = 0; j < 4; ++j) acc[4 + i][j] = MFMA16(bv[j], avhi[i], acc[4 + i][j]);
        __builtin_amdgcn_s_setprio(0);
    }
    #undef STAGE_A
    #undef STAGE_B
    #undef ABUF
    #undef BBUF

    // ---- epilogue: two 128-row halves through 64 KB swizzled LDS -> coalesced stores ----
    char* L = Lb;   // [128 rows][512 B], chunk16 ^= (row&31)

    float4 bias4[4];
    #pragma unroll
    for (int n = 0; n < 4; ++n)
        bias4[n] = *(const float4*)&bias[col0 + wn * 64 + n * 16 + kg * 4];

    #pragma unroll
    for (int h = 0; h < 2; ++h) {
        __syncthreads();   // h=0: K-loop LDS reads done; h=1: prior readback done
        if (wm == h) {
            #pragma unroll
            for (int m = 0; m < 8; ++m) {
                const int row_l = m * 16 + fr;                 // 0..127 local
                const long grow = (row0 + h * 128 + row_l) * (long)N;
                #pragma unroll
                for (int n = 0; n < 4; ++n) {
                    const int colr = wn * 64 + n * 16 + kg * 4;
                    float v0 = acc[m][n][0] + bias4[n].x;
                    float v1 = acc[m][n][1] + bias4[n].y;
                    float v2 = acc[m][n][2] + bias4[n].z;
                    float v3 = acc[m][n][3] + bias4[n].w;
                    if constexpr (EPI == 1) {
                        v0 = fmaxf(v0, 0.f); v1 = fmaxf(v1, 0.f);
                        v2 = fmaxf(v2, 0.f); v3 = fmaxf(v3, 0.f);
                    }
                    if constexpr (EPI == 2) {
                        if constexpr (sizeof(ResT) == 4) {
                            float4 r4 = *(const float4*)&Res[grow + col0 + colr];
                            v0 += r4.x; v1 += r4.y; v2 += r4.z; v3 += r4.w;
                        } else {
                            ushort4 r4 = *(const ushort4*)&Res[grow + col0 + colr];
                            v0 += b2f(r4.x); v1 += b2f(r4.y); v2 += b2f(r4.z); v3 += b2f(r4.w);
                        }
                    }
                    ushort4 pk; pk.x = f2b(v0); pk.y = f2b(v1); pk.z = f2b(v2); pk.w = f2b(v3);
                    const int cbyte = colr * 2;
                    const int chunk = cbyte >> 4;
                    *(ushort4*)(L + row_l * 512 + ((chunk ^ (row_l & 31)) << 4) + (cbyte & 15)) = pk;
                }
            }
        }
        __syncthreads();
        const int row_l = tid >> 2;   // 0..127
        const long grow2 = (row0 + h * 128 + row_l) * (long)N + col0;
        #pragma unroll
        for (int k2 = 0; k2 < 8; ++k2) {
            const int chunk = k2 * 4 + (tid & 3);
            short8 d = *(const short8*)(L + row_l * 512 + ((chunk ^ (row_l & 31)) << 4));
            *(short8*)&C[grow2 + chunk * 8] = d;
        }
    }
}

// ---------------- attention v2: one 256-thread block per WINDOW (16 heads) -------------
__global__ __launch_bounds__(256)
void attn_kernel(const ushort_t* __restrict__ qkv, ushort_t* __restrict__ o)
{
    __shared__ __align__(16) ushort_t sq[21504];   // 7 x 3072 contiguous slab
    __shared__ float pS[4][7][8];
    const int tid = threadIdx.x, wave = tid >> 6, lane = tid & 63;
    const long t0 = (long)blockIdx.x * 7;
    const ushort_t* src = qkv + t0 * 3072;

    #pragma unroll
    for (int r = 0; r < 10; ++r)
        GLOAD(src + (r * 256 + tid) * 8, &sq[0] + (size_t)(r * 256 + wave * 64) * 8);
    if (tid < 128)
        GLOAD(src + (2560 + tid) * 8, &sq[0] + (size_t)(2560 + wave * 64) * 8);
    __syncthreads();

    const int fr = lane & 15, kg = lane >> 4;
    const int fr7 = fr < 7 ? fr : 0;

    for (int it = 0; it < 4; ++it) {
        const int h = it * 4 + wave;
        const ushort_t* qrow = &sq[fr7 * 3072 + h * 64];
        const ushort_t* krow = &sq[fr7 * 3072 + 1024 + h * 64];
        short8 qf0 = *(const short8*)(qrow + kg * 8);
        short8 qf1 = *(const short8*)(qrow + 32 + kg * 8);
        short8 kf0 = *(const short8*)(krow + kg * 8);
        short8 kf1 = *(const short8*)(krow + 32 + kg * 8);
        f32x4 s = {};
        s = MFMA16(kf0, qf0, s);
        s = MFMA16(kf1, qf1, s);
        float sv[4];
        #pragma unroll
        for (int r = 0; r < 4; ++r) {
            int kidx = kg * 4 + r;
            sv[r] = (kidx < 7) ? s[r] * 0.125f : -3.0e38f;
        }
        float m = fmaxf(fmaxf(sv[0], sv[1]), fmaxf(sv[2], sv[3]));
        m = fmaxf(m, __shfl_xor(m, 16, 64));
        m = fmaxf(m, __shfl_xor(m, 32, 64));
        float e0 = __expf(sv[0] - m), e1 = __expf(sv[1] - m);
        float e2 = __expf(sv[2] - m), e3 = __expf(sv[3] - m);
        float den = e0 + e1 + e2 + e3;
        den += __shfl_xor(den, 16, 64);
        den += __shfl_xor(den, 32, 64);
        float inv = 1.f / den;
        if (fr < 7) {
            int kb = kg * 4;
            if (kb + 0 < 7) pS[wave][fr][kb + 0] = e0 * inv;
            if (kb + 1 < 7) pS[wave][fr][kb + 1] = e1 * inv;
            if (kb + 2 < 7) pS[wave][fr][kb + 2] = e2 * inv;
            if (kb + 3 < 7) pS[wave][fr][kb + 3] = e3 * inv;
        }
        float vj[7];
        #pragma unroll
        for (int j = 0; j < 7; ++j)
            vj[j] = b2f(sq[j * 3072 + 2048 + h * 64 + lane]);
        ushort_t* ob = o + t0 * 1024 + h * 64 + lane;
        #pragma unroll
        for (int i = 0; i < 7; ++i) {
            float a = 0.f;
            #pragma unroll
            for (int j = 0; j < 7; ++j) a += pS[wave][i][j] * vj[j];
            ob[(long)i * 1024] = f2b(a);
        }
    }
}

// ---------------- row LayerNorm over H=1024; 256 threads, 4 elems/thread ----------------
template<typename OutT>
__global__ __launch_bounds__(256)
void ln_kernel(const ushort_t* in, OutT* out,
               const float* __restrict__ g, const float* __restrict__ b)
{
    const long row = blockIdx.x;
    const int tid = threadIdx.x;
    const ushort_t* p = in + row * H_;
    ushort4 raw = ((const ushort4*)p)[tid];
    float x0 = b2f(raw.x), x1 = b2f(raw.y), x2 = b2f(raw.z), x3 = b2f(raw.w);
    float s  = x0 + x1 + x2 + x3;
    float ss = x0*x0 + x1*x1 + x2*x2 + x3*x3;
    #pragma unroll
    for (int off = 32; off > 0; off >>= 1) {
        s  += __shfl_down(s,  off, 64);
        ss += __shfl_down(ss, off, 64);
    }
    __shared__ float rs[4], rss[4];
    const int wave = tid >> 6, lane = tid & 63;
    if (lane == 0) { rs[wave] = s; rss[wave] = ss; }
    __syncthreads();
    float S  = rs[0] + rs[1] + rs[2] + rs[3];
    float SS = rss[0] + rss[1] + rss[2] + rss[3];
    float mean = S * (1.f / 1024.f);
    float var  = SS * (1.f / 1024.f) - mean * mean;
    float inv  = rsqrtf(var + 1e-5f);
    float4 gv = ((const float4*)g)[tid];
    float4 bvv = ((const float4*)b)[tid];
    float y0 = (x0 - mean) * inv * gv.x + bvv.x;
    float y1 = (x1 - mean) * inv * gv.y + bvv.y;
    float y2 = (x2 - mean) * inv * gv.z + bvv.z;
    float y3 = (x3 - mean) * inv * gv.w + bvv.w;
    if constexpr (sizeof(OutT) == 2) {
        ushort4 ov; ov.x = f2b(y0); ov.y = f2b(y1); ov.z = f2b(y2); ov.w = f2b(y3);
        ((ushort4*)out)[row * 256 + tid] = ov;
    } else {
        float4 ov; ov.x = y0; ov.y = y1; ov.z = y2; ov.w = y3;
        ((float4*)out)[row * 256 + tid] = ov;
    }
}

// ---------------- launch ----------------
extern "C" void kernel_launch(void* const* d_in, const int* in_sizes, int n_in,
                              void* d_out, int out_size, void* d_ws, size_t ws_size,
                              hipStream_t stream)
{
    const float* x      = (const float*)d_in[0];
    const float* wqkv_f = (const float*)d_in[1];
    const float* bqkv   = (const float*)d_in[2];
    const float* wout_f = (const float*)d_in[3];
    const float* bout   = (const float*)d_in[4];
    const float* ln1g   = (const float*)d_in[5];
    const float* ln1b   = (const float*)d_in[6];
    const float* ln2g   = (const float*)d_in[7];
    const float* ln2b   = (const float*)d_in[8];
    const float* wff1_f = (const float*)d_in[9];
    const float* bff1   = (const float*)d_in[10];
    const float* wff2_f = (const float*)d_in[11];
    const float* bff2   = (const float*)d_in[12];
    float* out = (float*)d_out;

    const size_t WQKV_N = 3072l * 1024, WOUT_N = 1024l * 1024;
    const size_t WFF1_N = 4096l * 1024, WFF2_N = 1024l * 4096;
    const size_t welems = WQKV_N + WOUT_N + WFF1_N + WFF2_N;

    // chunk rows R: multiple of lcm(7,256)=1792; arena = R*12288 B (s2 aliases xb) + weights
    int nc = 1;
    while (nc < 16 && (size_t)(MTOT / nc) * 12288 + welems * 2 > ws_size) nc <<= 1;
    const long R = MTOT / nc;

    char* ws = (char*)d_ws;
    ushort_t* qkv  = (ushort_t*)ws;                          // [R,3072]
    ushort_t* obuf = (ushort_t*)(ws + (size_t)R * 3072 * 2); // [R,1024]
    ushort_t* ff   = qkv;                                    // [R,4096] reuses qkv+obuf
    ushort_t* ybuf = (ushort_t*)(ws + (size_t)R * 4096 * 2); // [R,1024]
    ushort_t* xb   = (ushort_t*)(ws + (size_t)R * 5120 * 2); // [R,1024]
    ushort_t* s2   = xb;                                     // alias: xb dead after wo-GEMM
    ushort_t* wq   = (ushort_t*)(ws + (size_t)R * 6144 * 2);
    ushort_t* wo   = wq + WQKV_N;
    ushort_t* w1   = wo + WOUT_N;
    ushort_t* w2   = w1 + WFF1_N;

    f2b4_kernel<<<12288, 256, 0, stream>>>(wqkv_f, wq, wout_f, wo, wff1_f, w1, wff2_f, w2);

    for (int c = 0; c < nc; ++c) {
        const float* xc = x + (size_t)c * R * H_;
        float* oc = out + (size_t)c * R * H_;
        const int GY = R / 256;
        f2b_kernel<<<(R * H_) / 1024, 256, 0, stream>>>(xc, xb);
        // qkv = x @ Wqkv^T + b
        gemm_bt<0, float><<<12 * GY, 512, 0, stream>>>(xb, wq, bqkv, (const float*)nullptr, qkv, 3072, 1024, 12);
        // windowed attention (one block per window)
        attn_kernel<<<R / 7, 256, 0, stream>>>(qkv, obuf);
        // s1 = x + o @ Wout^T + b   (residual from bf16 xb)
        gemm_bt<2, ushort_t><<<4 * GY, 512, 0, stream>>>(obuf, wo, bout, xb, ybuf, 1024, 1024, 4);
        // y = LN1(s1), in place
        ln_kernel<ushort_t><<<R, 256, 0, stream>>>(ybuf, ybuf, ln1g, ln1b);
        // ff = relu(y @ W1^T + b1)
        gemm_bt<1, float><<<16 * GY, 512, 0, stream>>>(ybuf, w1, bff1, (const float*)nullptr, ff, 4096, 1024, 16);
        // s2 = y + ff @ W2^T + b2   (s2 aliases xb -- xb last read at wo-GEMM)
        gemm_bt<2, ushort_t><<<4 * GY, 512, 0, stream>>>(ff, w2, bff2, ybuf, s2, 1024, 4096, 4);
        // out = LN2(s2), fp32
        ln_kernel<float><<<R, 256, 0, stream>>>(s2, oc, ln2g, ln2b);
    }
}

// Round 17
// 905.613 us; speedup vs baseline: 1.0547x; 1.0547x over previous
//
#include <hip/hip_runtime.h>

typedef unsigned short ushort_t;
typedef __attribute__((ext_vector_type(8))) short short8;
typedef __attribute__((ext_vector_type(4))) float f32x4;

#define MTOT 28672   // B*S = 8*3584
#define H_   1024

static __device__ __forceinline__ float b2f(ushort_t u) {
    return __uint_as_float(((unsigned)u) << 16);
}
static __device__ __forceinline__ ushort_t f2b(float f) {
    unsigned u = __float_as_uint(f);
    u += 0x7fffu + ((u >> 16) & 1u);
    return (ushort_t)(u >> 16);
}

#define GLOAD(src, dst) __builtin_amdgcn_global_load_lds( \
    (const __attribute__((address_space(1))) void*)(src), \
    (__attribute__((address_space(3))) void*)(dst), 16, 0, 0)
#define MFMA16(a, b, c) __builtin_amdgcn_mfma_f32_16x16x32_bf16(a, b, c, 0, 0, 0)
#define LGKM0_FENCE() do { \
    asm volatile("s_waitcnt lgkmcnt(0)" ::: "memory"); \
    __builtin_amdgcn_sched_barrier(0); } while (0)

// ---------------- fp32 -> bf16 conversion (n % 1024 == 0), 4 elems/thread ----------------
__global__ __launch_bounds__(256)
void f2b_kernel(const float* __restrict__ in, ushort_t* __restrict__ out)
{
    size_t i = (size_t)blockIdx.x * 256 + threadIdx.x;
    float4 v = ((const float4*)in)[i];
    ushort4 o;
    o.x = f2b(v.x); o.y = f2b(v.y); o.z = f2b(v.z); o.w = f2b(v.w);
    ((ushort4*)out)[i] = o;
}

// ---------------- merged weight conversion: 4 segments, one launch ----------------
__global__ __launch_bounds__(256)
void f2b4_kernel(const float* __restrict__ s0, ushort_t* __restrict__ d0,
                 const float* __restrict__ s1, ushort_t* __restrict__ d1,
                 const float* __restrict__ s2, ushort_t* __restrict__ d2,
                 const float* __restrict__ s3, ushort_t* __restrict__ d3)
{
    size_t i = (size_t)blockIdx.x * 256 + threadIdx.x;   // grid = 12288 blocks exactly
    const float* s; ushort_t* d; size_t off;
    if (i < 786432)            { s = s0; d = d0; off = i; }
    else if (i < 1048576)      { s = s1; d = d1; off = i - 786432; }
    else if (i < 2097152)      { s = s2; d = d2; off = i - 1048576; }
    else                       { s = s3; d = d3; off = i - 2097152; }
    float4 v = ((const float4*)s)[off];
    ushort4 o;
    o.x = f2b(v.x); o.y = f2b(v.y); o.z = f2b(v.z); o.w = f2b(v.w);
    ((ushort4*)d)[off] = o;
}

// ---------------- bf16 GEMM v7 FINAL: BM=BN=256, BK=64, 8 waves (2m x 4n) -------------
// Measured basin optimum for K=1024 (R1-R16 ledger: v4~v7 247-249us/42% MfmaUtil;
// v5,v6,v8,v9,v10,v10b,v11 all worse). 128 KB LDS double-buffer, 4 phases/K64 tile:
// pre-barrier ds_reads (data established at prev phase's barrier) + 2-GLOAD region
// stage; counted vmcnt(4) at odd phases; post-barrier lgkmcnt(0)+sched_barrier(0)
// (rule #18); setprio around each 16-MFMA cluster. Conflict-free chunk swizzle
// pos = kk ^ ((r>>1)&3). Swapped-operand MFMA (lane holds 4 consecutive cols) +
// swizzled-LDS transpose epilogue -> 64B-contiguous stores.
template<int EPI, typename ResT>
__global__ __launch_bounds__(512, 1)
void gemm_bt(const ushort_t* __restrict__ A, const ushort_t* __restrict__ Bt,
             const float* __restrict__ bias, const ResT* __restrict__ Res,
             ushort_t* __restrict__ C, int N, int K, int GX)
{
    __shared__ __align__(16) ushort_t lds[2][4][8192];   // 128 KB
    const int tid  = threadIdx.x;
    const int wave = tid >> 6;
    const int lane = tid & 63;
    const int wm = wave >> 2, wn = wave & 3;   // 2x4 waves, each 128 rows x 64 cols
    const int fr = lane & 15, kg = lane >> 4;

    // bijective XCD-chunked swizzle (m204 form)
    const int nwg = gridDim.x;
    const int xcd = blockIdx.x & 7, ofs = blockIdx.x >> 3;
    const int q8 = nwg >> 3, r8 = nwg & 7;
    const int wg = (xcd < r8 ? xcd * (q8 + 1) : r8 * (q8 + 1) + (xcd - r8) * q8) + ofs;
    const long row0 = (long)(wg / GX) * 256;
    const long col0 = (long)(wg % GX) * 256;

    const int NT = K >> 6;

    // staging: per region 1024 chunks = 512 threads x 2 rounds (round1 = +128 rows)
    const int sr_ = tid >> 2;
    const int kk_ = (tid & 3) ^ ((sr_ >> 1) & 3);
    const ushort_t* pa = A  + (row0 + sr_) * (size_t)K + kk_ * 8;
    const ushort_t* pb = Bt + (col0 + sr_) * (size_t)K + kk_ * 8;
    const size_t rstep = (size_t)128 * K;

    // prologue: tile 0, regions in strict order 0,1,2,3; establish r0,r1 before loop
    {
        ushort_t* d0 = &lds[0][0][0] + wave * 512;
        ushort_t* d1 = &lds[0][1][0] + wave * 512;
        ushort_t* d2 = &lds[0][2][0] + wave * 512;
        ushort_t* d3 = &lds[0][3][0] + wave * 512;
        GLOAD(pa,            d0); GLOAD(pa + rstep,      d0 + 4096);
        GLOAD(pb,            d1); GLOAD(pb + rstep,      d1 + 4096);
        GLOAD(pa + 32,       d2); GLOAD(pa + 32 + rstep, d2 + 4096);
        GLOAD(pb + 32,       d3); GLOAD(pb + 32 + rstep, d3 + 4096);
    }
    asm volatile("s_waitcnt vmcnt(4)" ::: "memory");
    asm volatile("s_barrier" ::: "memory");

    // per-lane ds_read byte offsets
    const int pos2  = kg ^ ((fr >> 1) & 3);
    const int abase = (wm * 128 + fr) * 64 + pos2 * 16;   // + m*1024
    const int bbase = (wn * 64  + fr) * 64 + pos2 * 16;   // + n*1024

    f32x4 acc[8][4] = {};

    for (int t = 0; t < NT; ++t) {
        const int b = t & 1;
        const bool pf = (t + 1 < NT);
        const size_t go = (size_t)(t + 1) * 64;
        const char* rA0 = (const char*)&lds[b][0][0];
        const char* rB0 = (const char*)&lds[b][1][0];
        const char* rA1 = (const char*)&lds[b][2][0];
        const char* rB1 = (const char*)&lds[b][3][0];
        ushort_t* d0 = &lds[1 - b][0][0] + wave * 512;
        ushort_t* d1 = &lds[1 - b][1][0] + wave * 512;
        ushort_t* d2 = &lds[1 - b][2][0] + wave * 512;
        ushort_t* d3 = &lds[1 - b][3][0] + wave * 512;

        short8 bv[4], avlo[4], avhi[4];

        // ===== phase 0 =====
        #pragma unroll
        for (int j = 0; j < 4; ++j) bv[j]   = *(const short8*)(rB0 + bbase + j * 1024);
        #pragma unroll
        for (int i = 0; i < 4; ++i) avlo[i] = *(const short8*)(rA0 + abase + i * 1024);
        if (pf) { GLOAD(pa + go, d0); GLOAD(pa + go + rstep, d0 + 4096); }
        asm volatile("s_barrier" ::: "memory");
        LGKM0_FENCE();
        __builtin_amdgcn_s_setprio(1);
        #pragma unroll
        for (int i = 0; i < 4; ++i)
            #pragma unroll
            for (int j = 0; j < 4; ++j) acc[i][j] = MFMA16(bv[j], avlo[i], acc[i][j]);
        __builtin_amdgcn_s_setprio(0);

        // ===== phase 1 =====
        #pragma unroll
        for (int i = 0; i < 4; ++i) avhi[i] = *(const short8*)(rA0 + abase + (4 + i) * 1024);
        if (pf) { GLOAD(pb + go, d1); GLOAD(pb + go + rstep, d1 + 4096); }
        if (pf) { asm volatile("s_waitcnt vmcnt(4)" ::: "memory"); }
        else    { asm volatile("s_waitcnt vmcnt(0)" ::: "memory"); }
        asm volatile("s_barrier" ::: "memory");
        LGKM0_FENCE();
        __builtin_amdgcn_s_setprio(1);
        #pragma unroll
        for (int i = 0; i < 4; ++i)
            #pragma unroll
            for (int j = 0; j < 4; ++j) acc[4 + i][j] = MFMA16(bv[j], avhi[i], acc[4 + i][j]);
        __builtin_amdgcn_s_setprio(0);

        // ===== phase 2 =====
        #pragma unroll
        for (int j = 0; j < 4; ++j) bv[j]   = *(const short8*)(rB1 + bbase + j * 1024);
        #pragma unroll
        for (int i = 0; i < 4; ++i) avlo[i] = *(const short8*)(rA1 + abase + i * 1024);
        if (pf) { GLOAD(pa + go + 32, d2); GLOAD(pa + go + 32 + rstep, d2 + 4096); }
        asm volatile("s_barrier" ::: "memory");
        LGKM0_FENCE();
        __builtin_amdgcn_s_setprio(1);
        #pragma unroll
        for (int i = 0; i < 4; ++i)
            #pragma unroll
            for (int j = 0; j < 4; ++j) acc[i][j] = MFMA16(bv[j], avlo[i], acc[i][j]);
        __builtin_amdgcn_s_setprio(0);

        // ===== phase 3 =====
        #pragma unroll
        for (int i = 0; i < 4; ++i) avhi[i] = *(const short8*)(rA1 + abase + (4 + i) * 1024);
        if (pf) { GLOAD(pb + go + 32, d3); GLOAD(pb + go + 32 + rstep, d3 + 4096); }
        if (pf) { asm volatile("s_waitcnt vmcnt(4)" ::: "memory"); }
        asm volatile("s_barrier" ::: "memory");
        LGKM0_FENCE();
        __builtin_amdgcn_s_setprio(1);
        #pragma unroll
        for (int i = 0; i < 4; ++i)
            #pragma unroll
            for (int j = 0; j < 4; ++j) acc[4 + i][j] = MFMA16(bv[j], avhi[i], acc[4 + i][j]);
        __builtin_amdgcn_s_setprio(0);
    }

    // ---- epilogue: swapped layout -> swizzled LDS bf16 tile -> coalesced stores ----
    __syncthreads();
    char* L = (char*)&lds[0][0][0];   // [256 rows][512 B], chunk16 ^= (row&31)

    float4 bias4[4];
    #pragma unroll
    for (int n = 0; n < 4; ++n)
        bias4[n] = *(const float4*)&bias[col0 + wn * 64 + n * 16 + kg * 4];

    #pragma unroll
    for (int m = 0; m < 8; ++m) {
        const int row_t = wm * 128 + m * 16 + fr;
        const long grow = (row0 + row_t) * (long)N;
        #pragma unroll
        for (int n = 0; n < 4; ++n) {
            const int colr = wn * 64 + n * 16 + kg * 4;
            float v0 = acc[m][n][0] + bias4[n].x;
            float v1 = acc[m][n][1] + bias4[n].y;
            float v2 = acc[m][n][2] + bias4[n].z;
            float v3 = acc[m][n][3] + bias4[n].w;
            if constexpr (EPI == 1) {
                v0 = fmaxf(v0, 0.f); v1 = fmaxf(v1, 0.f);
                v2 = fmaxf(v2, 0.f); v3 = fmaxf(v3, 0.f);
            }
            if constexpr (EPI == 2) {
                if constexpr (sizeof(ResT) == 4) {
                    float4 r4 = *(const float4*)&Res[grow + col0 + colr];
                    v0 += r4.x; v1 += r4.y; v2 += r4.z; v3 += r4.w;
                } else {
                    ushort4 r4 = *(const ushort4*)&Res[grow + col0 + colr];
                    v0 += b2f(r4.x); v1 += b2f(r4.y); v2 += b2f(r4.z); v3 += b2f(r4.w);
                }
            }
            ushort4 pk; pk.x = f2b(v0); pk.y = f2b(v1); pk.z = f2b(v2); pk.w = f2b(v3);
            const int cbyte = colr * 2;
            const int chunk = cbyte >> 4;
            const int addr  = row_t * 512 + ((chunk ^ (row_t & 31)) << 4) + (cbyte & 15);
            *(ushort4*)(L + addr) = pk;
        }
    }
    __syncthreads();

    #pragma unroll
    for (int p = 0; p < 2; ++p) {
        const int row_t = p * 128 + (tid >> 2);
        const long grow = (row0 + row_t) * (long)N + col0;
        #pragma unroll
        for (int k = 0; k < 8; ++k) {
            const int chunk = k * 4 + (tid & 3);
            short8 d = *(const short8*)(L + row_t * 512 + ((chunk ^ (row_t & 31)) << 4));
            *(short8*)&C[grow + chunk * 8] = d;
        }
    }
}

// ---------------- attention v2: one 256-thread block per WINDOW (16 heads) -------------
__global__ __launch_bounds__(256)
void attn_kernel(const ushort_t* __restrict__ qkv, ushort_t* __restrict__ o)
{
    __shared__ __align__(16) ushort_t sq[21504];   // 7 x 3072 contiguous slab
    __shared__ float pS[4][7][8];
    const int tid = threadIdx.x, wave = tid >> 6, lane = tid & 63;
    const long t0 = (long)blockIdx.x * 7;
    const ushort_t* src = qkv + t0 * 3072;

    #pragma unroll
    for (int r = 0; r < 10; ++r)
        GLOAD(src + (r * 256 + tid) * 8, &sq[0] + (size_t)(r * 256 + wave * 64) * 8);
    if (tid < 128)
        GLOAD(src + (2560 + tid) * 8, &sq[0] + (size_t)(2560 + wave * 64) * 8);
    __syncthreads();

    const int fr = lane & 15, kg = lane >> 4;
    const int fr7 = fr < 7 ? fr : 0;

    for (int it = 0; it < 4; ++it) {
        const int h = it * 4 + wave;
        const ushort_t* qrow = &sq[fr7 * 3072 + h * 64];
        const ushort_t* krow = &sq[fr7 * 3072 + 1024 + h * 64];
        short8 qf0 = *(const short8*)(qrow + kg * 8);
        short8 qf1 = *(const short8*)(qrow + 32 + kg * 8);
        short8 kf0 = *(const short8*)(krow + kg * 8);
        short8 kf1 = *(const short8*)(krow + 32 + kg * 8);
        f32x4 s = {};
        s = MFMA16(kf0, qf0, s);
        s = MFMA16(kf1, qf1, s);
        float sv[4];
        #pragma unroll
        for (int r = 0; r < 4; ++r) {
            int kidx = kg * 4 + r;
            sv[r] = (kidx < 7) ? s[r] * 0.125f : -3.0e38f;
        }
        float m = fmaxf(fmaxf(sv[0], sv[1]), fmaxf(sv[2], sv[3]));
        m = fmaxf(m, __shfl_xor(m, 16, 64));
        m = fmaxf(m, __shfl_xor(m, 32, 64));
        float e0 = __expf(sv[0] - m), e1 = __expf(sv[1] - m);
        float e2 = __expf(sv[2] - m), e3 = __expf(sv[3] - m);
        float den = e0 + e1 + e2 + e3;
        den += __shfl_xor(den, 16, 64);
        den += __shfl_xor(den, 32, 64);
        float inv = 1.f / den;
        if (fr < 7) {
            int kb = kg * 4;
            if (kb + 0 < 7) pS[wave][fr][kb + 0] = e0 * inv;
            if (kb + 1 < 7) pS[wave][fr][kb + 1] = e1 * inv;
            if (kb + 2 < 7) pS[wave][fr][kb + 2] = e2 * inv;
            if (kb + 3 < 7) pS[wave][fr][kb + 3] = e3 * inv;
        }
        float vj[7];
        #pragma unroll
        for (int j = 0; j < 7; ++j)
            vj[j] = b2f(sq[j * 3072 + 2048 + h * 64 + lane]);
        ushort_t* ob = o + t0 * 1024 + h * 64 + lane;
        #pragma unroll
        for (int i = 0; i < 7; ++i) {
            float a = 0.f;
            #pragma unroll
            for (int j = 0; j < 7; ++j) a += pS[wave][i][j] * vj[j];
            ob[(long)i * 1024] = f2b(a);
        }
    }
}

// ---------------- row LayerNorm over H=1024; 256 threads, 4 elems/thread ----------------
template<typename OutT>
__global__ __launch_bounds__(256)
void ln_kernel(const ushort_t* in, OutT* out,
               const float* __restrict__ g, const float* __restrict__ b)
{
    const long row = blockIdx.x;
    const int tid = threadIdx.x;
    const ushort_t* p = in + row * H_;
    ushort4 raw = ((const ushort4*)p)[tid];
    float x0 = b2f(raw.x), x1 = b2f(raw.y), x2 = b2f(raw.z), x3 = b2f(raw.w);
    float s  = x0 + x1 + x2 + x3;
    float ss = x0*x0 + x1*x1 + x2*x2 + x3*x3;
    #pragma unroll
    for (int off = 32; off > 0; off >>= 1) {
        s  += __shfl_down(s,  off, 64);
        ss += __shfl_down(ss, off, 64);
    }
    __shared__ float rs[4], rss[4];
    const int wave = tid >> 6, lane = tid & 63;
    if (lane == 0) { rs[wave] = s; rss[wave] = ss; }
    __syncthreads();
    float S  = rs[0] + rs[1] + rs[2] + rs[3];
    float SS = rss[0] + rss[1] + rss[2] + rss[3];
    float mean = S * (1.f / 1024.f);
    float var  = SS * (1.f / 1024.f) - mean * mean;
    float inv  = rsqrtf(var + 1e-5f);
    float4 gv = ((const float4*)g)[tid];
    float4 bvv = ((const float4*)b)[tid];
    float y0 = (x0 - mean) * inv * gv.x + bvv.x;
    float y1 = (x1 - mean) * inv * gv.y + bvv.y;
    float y2 = (x2 - mean) * inv * gv.z + bvv.z;
    float y3 = (x3 - mean) * inv * gv.w + bvv.w;
    if constexpr (sizeof(OutT) == 2) {
        ushort4 ov; ov.x = f2b(y0); ov.y = f2b(y1); ov.z = f2b(y2); ov.w = f2b(y3);
        ((ushort4*)out)[row * 256 + tid] = ov;
    } else {
        float4 ov; ov.x = y0; ov.y = y1; ov.z = y2; ov.w = y3;
        ((float4*)out)[row * 256 + tid] = ov;
    }
}

// ---------------- launch ----------------
extern "C" void kernel_launch(void* const* d_in, const int* in_sizes, int n_in,
                              void* d_out, int out_size, void* d_ws, size_t ws_size,
                              hipStream_t stream)
{
    const float* x      = (const float*)d_in[0];
    const float* wqkv_f = (const float*)d_in[1];
    const float* bqkv   = (const float*)d_in[2];
    const float* wout_f = (const float*)d_in[3];
    const float* bout   = (const float*)d_in[4];
    const float* ln1g   = (const float*)d_in[5];
    const float* ln1b   = (const float*)d_in[6];
    const float* ln2g   = (const float*)d_in[7];
    const float* ln2b   = (const float*)d_in[8];
    const float* wff1_f = (const float*)d_in[9];
    const float* bff1   = (const float*)d_in[10];
    const float* wff2_f = (const float*)d_in[11];
    const float* bff2   = (const float*)d_in[12];
    float* out = (float*)d_out;

    const size_t WQKV_N = 3072l * 1024, WOUT_N = 1024l * 1024;
    const size_t WFF1_N = 4096l * 1024, WFF2_N = 1024l * 4096;
    const size_t welems = WQKV_N + WOUT_N + WFF1_N + WFF2_N;

    // chunk rows R: multiple of lcm(7,256)=1792; arena = R*12288 B (s2 aliases xb) + weights
    int nc = 1;
    while (nc < 16 && (size_t)(MTOT / nc) * 12288 + welems * 2 > ws_size) nc <<= 1;
    const long R = MTOT / nc;

    char* ws = (char*)d_ws;
    ushort_t* qkv  = (ushort_t*)ws;                          // [R,3072]
    ushort_t* obuf = (ushort_t*)(ws + (size_t)R * 3072 * 2); // [R,1024]
    ushort_t* ff   = qkv;                                    // [R,4096] reuses qkv+obuf
    ushort_t* ybuf = (ushort_t*)(ws + (size_t)R * 4096 * 2); // [R,1024]
    ushort_t* xb   = (ushort_t*)(ws + (size_t)R * 5120 * 2); // [R,1024]
    ushort_t* s2   = xb;                                     // alias: xb dead after wo-GEMM
    ushort_t* wq   = (ushort_t*)(ws + (size_t)R * 6144 * 2);
    ushort_t* wo   = wq + WQKV_N;
    ushort_t* w1   = wo + WOUT_N;
    ushort_t* w2   = w1 + WFF1_N;

    f2b4_kernel<<<12288, 256, 0, stream>>>(wqkv_f, wq, wout_f, wo, wff1_f, w1, wff2_f, w2);

    for (int c = 0; c < nc; ++c) {
        const float* xc = x + (size_t)c * R * H_;
        float* oc = out + (size_t)c * R * H_;
        const int GY = R / 256;
        f2b_kernel<<<(R * H_) / 1024, 256, 0, stream>>>(xc, xb);
        // qkv = x @ Wqkv^T + b
        gemm_bt<0, float><<<12 * GY, 512, 0, stream>>>(xb, wq, bqkv, (const float*)nullptr, qkv, 3072, 1024, 12);
        // windowed attention (one block per window)
        attn_kernel<<<R / 7, 256, 0, stream>>>(qkv, obuf);
        // s1 = x + o @ Wout^T + b   (residual from bf16 xb)
        gemm_bt<2, ushort_t><<<4 * GY, 512, 0, stream>>>(obuf, wo, bout, xb, ybuf, 1024, 1024, 4);
        // y = LN1(s1), in place
        ln_kernel<ushort_t><<<R, 256, 0, stream>>>(ybuf, ybuf, ln1g, ln1b);
        // ff = relu(y @ W1^T + b1)
        gemm_bt<1, float><<<16 * GY, 512, 0, stream>>>(ybuf, w1, bff1, (const float*)nullptr, ff, 4096, 1024, 16);
        // s2 = y + ff @ W2^T + b2   (s2 aliases xb -- xb last read at wo-GEMM)
        gemm_bt<2, ushort_t><<<4 * GY, 512, 0, stream>>>(ff, w2, bff2, ybuf, s2, 1024, 4096, 4);
        // out = LN2(s2), fp32
        ln_kernel<float><<<R, 256, 0, stream>>>(s2, oc, ln2g, ln2b);
    }
}